// Round 3
// baseline (837.514 us; speedup 1.0000x reference)
//
#include <hip/hip_runtime.h>
#include <cstddef>

// B=2, CI=CO=64, NS=16, NPTS=1024
constexpr int P_TOTAL = 32768;   // total points
constexpr int NCH     = 64;
constexpr int PPB     = 16;      // points per block
constexpr int PPW     = 4;       // points per wave (4 waves/block)
constexpr int XPAD    = 68;      // xt row stride (floats), 16B-aligned

// y[o,p] = b[o] + sum_i W[o,i]*x[i,p]*(1 + 0.1*eps[p,o,i])
//
// Coalescing identity: viewing eps[p] (64x64 row-major) as 1024 float4s,
// flat index q = k*64 + lane maps to (o = q>>4, i0 = 4*(q&15)) — and W's
// flat float4 q is exactly W[o][i0..i0+3]. So fully-contiguous 1KB/instr
// wave loads of eps pair element-wise with Wl[q] from LDS, no permutation.
//
// LOW-VGPR restructure: eps row consumed in 4 chunks of 4 float4
// (2-deep chunk pipeline, 32 eps VGPRs instead of 64),
// __launch_bounds__(256,5) pins <=102 VGPR -> 5 blocks/CU (20 waves/CU).
// Grid = 2048 blocks. Nontemporal loads for the 537MB streamed-once eps;
// each lane's 4 point-outputs stored as one float4.

using vf4 = __attribute__((ext_vector_type(4))) float;

__global__ __launch_bounds__(256, 5) void noise_conv_kernel(
    const float* __restrict__ x, const float* __restrict__ W,
    const float* __restrict__ bias, const float* __restrict__ eps,
    float* __restrict__ out)
{
    __shared__ __align__(16) vf4   Wl[NCH * NCH / 4];  // 16 KB flat copy of W
    __shared__ __align__(16) float xt[PPB][XPAD];      // xt[j][i] = x[i, p0+j]

    const int tid  = threadIdx.x;
    const int lane = tid & 63;
    const int wv   = tid >> 6;        // 0..3
    const int p0   = blockIdx.x * PPB;
    const int g    = lane >> 4;       // 0..3  (o = 4k + g)
    const int s    = lane & 15;       // i-chunk: i0 = 4s

    // Stage W flat (coalesced global, contiguous b128 LDS writes).
    const vf4* W4 = reinterpret_cast<const vf4*>(W);
#pragma unroll
    for (int c = 0; c < 4; ++c) {
        int idx = c * 256 + tid;
        Wl[idx] = W4[idx];
    }
    // Stage x tile transposed: 16-lane groups read 64B contiguous rows.
#pragma unroll
    for (int c = 0; c < (PPB * NCH) / 256; ++c) {
        int e = c * 256 + tid;
        int i = e >> 4;               // 0..63
        int j = e & (PPB - 1);        // 0..15
        xt[j][i] = x[i * P_TOTAL + p0 + j];
    }

    const int   o_fin = 4 * s + g;    // channel this lane finally owns
    const float b_fin = bias[o_fin];

    __syncthreads();

    const int jj0 = wv * PPW;
    const vf4* ep_base = reinterpret_cast<const vf4*>(eps)
                       + (size_t)(p0 + jj0) * (NCH * NCH / 4) + lane;

    float y4[PPW];   // static-indexed (j loop fully unrolled)

#pragma unroll
    for (int j = 0; j < PPW; ++j) {
        const int jj = jj0 + j;
        const vf4* ep4 = ep_base + (size_t)j * (NCH * NCH / 4);

        const vf4 x4 = *reinterpret_cast<const vf4*>(&xt[jj][4 * s]);

        float acc[16];
        vf4 ea[4], eb[4];

        // Chunk pipeline: 2 chunks (8 float4 = 32 VGPR) in flight.
#pragma unroll
        for (int t = 0; t < 4; ++t)
            ea[t] = __builtin_nontemporal_load(ep4 + t * 64);
#pragma unroll
        for (int t = 0; t < 4; ++t)
            eb[t] = __builtin_nontemporal_load(ep4 + (4 + t) * 64);

        // compute k=0..3 from ea
#pragma unroll
        for (int t = 0; t < 4; ++t) {
            vf4 w4 = Wl[t * 64 + lane];           // contiguous b128, conflict-free
            vf4 e4 = ea[t];
            float wx0 = w4.x * x4.x, wx1 = w4.y * x4.y;
            float wx2 = w4.z * x4.z, wx3 = w4.w * x4.w;
            float f0 = fmaf(0.1f, e4.x, 1.0f);
            float f1 = fmaf(0.1f, e4.y, 1.0f);
            float f2 = fmaf(0.1f, e4.z, 1.0f);
            float f3 = fmaf(0.1f, e4.w, 1.0f);
            float a  = wx0 * f0;
            a = fmaf(wx1, f1, a);
            a = fmaf(wx2, f2, a);
            a = fmaf(wx3, f3, a);
            acc[t] = a;
        }
        // refill ea with chunk 2
#pragma unroll
        for (int t = 0; t < 4; ++t)
            ea[t] = __builtin_nontemporal_load(ep4 + (8 + t) * 64);
        // compute k=4..7 from eb
#pragma unroll
        for (int t = 0; t < 4; ++t) {
            int k = 4 + t;
            vf4 w4 = Wl[k * 64 + lane];
            vf4 e4 = eb[t];
            float wx0 = w4.x * x4.x, wx1 = w4.y * x4.y;
            float wx2 = w4.z * x4.z, wx3 = w4.w * x4.w;
            float f0 = fmaf(0.1f, e4.x, 1.0f);
            float f1 = fmaf(0.1f, e4.y, 1.0f);
            float f2 = fmaf(0.1f, e4.z, 1.0f);
            float f3 = fmaf(0.1f, e4.w, 1.0f);
            float a  = wx0 * f0;
            a = fmaf(wx1, f1, a);
            a = fmaf(wx2, f2, a);
            a = fmaf(wx3, f3, a);
            acc[k] = a;
        }
        // refill eb with chunk 3
#pragma unroll
        for (int t = 0; t < 4; ++t)
            eb[t] = __builtin_nontemporal_load(ep4 + (12 + t) * 64);
        // compute k=8..11 from ea
#pragma unroll
        for (int t = 0; t < 4; ++t) {
            int k = 8 + t;
            vf4 w4 = Wl[k * 64 + lane];
            vf4 e4 = ea[t];
            float wx0 = w4.x * x4.x, wx1 = w4.y * x4.y;
            float wx2 = w4.z * x4.z, wx3 = w4.w * x4.w;
            float f0 = fmaf(0.1f, e4.x, 1.0f);
            float f1 = fmaf(0.1f, e4.y, 1.0f);
            float f2 = fmaf(0.1f, e4.z, 1.0f);
            float f3 = fmaf(0.1f, e4.w, 1.0f);
            float a  = wx0 * f0;
            a = fmaf(wx1, f1, a);
            a = fmaf(wx2, f2, a);
            a = fmaf(wx3, f3, a);
            acc[k] = a;
        }
        // compute k=12..15 from eb
#pragma unroll
        for (int t = 0; t < 4; ++t) {
            int k = 12 + t;
            vf4 w4 = Wl[k * 64 + lane];
            vf4 e4 = eb[t];
            float wx0 = w4.x * x4.x, wx1 = w4.y * x4.y;
            float wx2 = w4.z * x4.z, wx3 = w4.w * x4.w;
            float f0 = fmaf(0.1f, e4.x, 1.0f);
            float f1 = fmaf(0.1f, e4.y, 1.0f);
            float f2 = fmaf(0.1f, e4.z, 1.0f);
            float f3 = fmaf(0.1f, e4.w, 1.0f);
            float a  = wx0 * f0;
            a = fmaf(wx1, f1, a);
            a = fmaf(wx2, f2, a);
            a = fmaf(wx3, f3, a);
            acc[k] = a;
        }

        // Reduce-scatter over the 16 i-chunk lanes (lane bits 0..3):
        // 15 shuffles; lane l ends holding the full sum for o = 4*(l&15)+(l>>4).
        float r8[8];
#pragma unroll
        for (int t = 0; t < 8; ++t) {
            float mine  = (s & 8) ? acc[t + 8] : acc[t];
            float other = (s & 8) ? acc[t]     : acc[t + 8];
            r8[t] = mine + __shfl_xor(other, 8, 64);
        }
        float r4[4];
#pragma unroll
        for (int t = 0; t < 4; ++t) {
            float mine  = (s & 4) ? r8[t + 4] : r8[t];
            float other = (s & 4) ? r8[t]     : r8[t + 4];
            r4[t] = mine + __shfl_xor(other, 4, 64);
        }
        float r2[2];
#pragma unroll
        for (int t = 0; t < 2; ++t) {
            float mine  = (s & 2) ? r4[t + 2] : r4[t];
            float other = (s & 2) ? r4[t]     : r4[t + 2];
            r2[t] = mine + __shfl_xor(other, 2, 64);
        }
        {
            float mine  = (s & 1) ? r2[1] : r2[0];
            float other = (s & 1) ? r2[0] : r2[1];
            y4[j] = mine + __shfl_xor(other, 1, 64) + b_fin;
        }
    }

    // One 16B store per lane covering its 4 consecutive points.
    vf4 yv;
    yv.x = y4[0]; yv.y = y4[1]; yv.z = y4[2]; yv.w = y4[3];
    __builtin_nontemporal_store(
        yv, reinterpret_cast<vf4*>(&out[(size_t)o_fin * P_TOTAL + p0 + jj0]));
}

extern "C" void kernel_launch(void* const* d_in, const int* in_sizes, int n_in,
                              void* d_out, int out_size, void* d_ws, size_t ws_size,
                              hipStream_t stream) {
    const float* x    = (const float*)d_in[0];  // [64, 32768] after reshape
    const float* W    = (const float*)d_in[1];  // [64,64]
    const float* bias = (const float*)d_in[2];  // [64]
    const float* eps  = (const float*)d_in[3];  // [32768,64,64]
    float* out        = (float*)d_out;          // [64, 32768]

    dim3 grid(P_TOTAL / PPB);   // 2048 blocks
    dim3 block(256);
    noise_conv_kernel<<<grid, block, 0, stream>>>(x, W, bias, eps, out);
}

// Round 4
// 688.195 us; speedup vs baseline: 1.2170x; 1.2170x over previous
//
#include <hip/hip_runtime.h>
#include <cstddef>

// B=2, CI=CO=64, NS=16, NPTS=1024
constexpr int P_TOTAL = 32768;   // total points
constexpr int NCH     = 64;
constexpr int PPB     = 16;      // points per block (all 4 waves share them)
constexpr int XPAD    = 68;      // xt row stride (floats), 272B = 17*16B aligned

// y[o,p] = b[o] + sum_i W[o,i]*x[i,p]*(1 + 0.1*eps[p,o,i])
//
// Quarter-split structure: wave w of each block owns channels
// o in [16w, 16w+16). For each point p it loads ONLY its contiguous 4KB
// quarter of the 16KB eps row:
//   float4 idx = p*1024 + 256*w + 64*t + lane,  t = 0..3
// (lane = 16g+s pairs element-wise with W4[256w + 64t + lane] = W[o][4s..4s+3],
//  o = 16w + 4t + g). Four 1KB fully-coalesced wave loads per point,
// one address register + immediate offsets. W quarter is held in 4 VGPR
// float4s (no LDS W reads). acc[4] instead of acc[16]. Low VGPR ->
// 5-6 waves/SIMD; loads pipelined across points (A/B buffers).
//
// Reduce: butterfly xor8+xor4 (all lanes, same index) then the proven
// cndmask reduce-scatter for xor2+xor1: lane (g,s) ends with the full sum
// for o = 16w + 4*(s&3) + g, replicated over s>>2. Replica s<4 stores a
// float4 of 4 consecutive points.

using vf4 = __attribute__((ext_vector_type(4))) float;

__device__ __forceinline__ float dot4(vf4 w4, vf4 x4, vf4 e4) {
    float f0 = fmaf(0.1f, e4.x, 1.0f);
    float f1 = fmaf(0.1f, e4.y, 1.0f);
    float f2 = fmaf(0.1f, e4.z, 1.0f);
    float f3 = fmaf(0.1f, e4.w, 1.0f);
    float a  = (w4.x * x4.x) * f0;
    a = fmaf(w4.y * x4.y, f1, a);
    a = fmaf(w4.z * x4.z, f2, a);
    a = fmaf(w4.w * x4.w, f3, a);
    return a;
}

__global__ __launch_bounds__(256) void noise_conv_kernel(
    const float* __restrict__ x, const float* __restrict__ W,
    const float* __restrict__ bias, const float* __restrict__ eps,
    float* __restrict__ out)
{
    __shared__ __align__(16) float xt[PPB][XPAD];   // xt[j][i] = x[i, p0+j]

    const int tid  = threadIdx.x;
    const int lane = tid & 63;
    const int w    = tid >> 6;        // wave id 0..3 -> channel slice
    const int g    = lane >> 4;       // 0..3
    const int s    = lane & 15;       // i-chunk: i0 = 4s
    const int p0   = blockIdx.x * PPB;

    // Stage x tile transposed: 16-lane groups read 64B contiguous row chunks.
#pragma unroll
    for (int c = 0; c < (PPB * NCH) / 256; ++c) {   // 4 iters
        int e = c * 256 + tid;
        int i = e >> 4;               // 0..63
        int j = e & (PPB - 1);        // 0..15
        xt[j][i] = x[i * P_TOTAL + p0 + j];
    }

    // This wave's W quarter in registers (16 KB array, L2-resident).
    const vf4* W4 = reinterpret_cast<const vf4*>(W);
    const vf4 Wr0 = W4[256 * w +   0 + lane];
    const vf4 Wr1 = W4[256 * w +  64 + lane];
    const vf4 Wr2 = W4[256 * w + 128 + lane];
    const vf4 Wr3 = W4[256 * w + 192 + lane];

    const int   o_fin = 16 * w + 4 * (s & 3) + g;
    const float b_fin = bias[o_fin];

    __syncthreads();

    const vf4* ebase = reinterpret_cast<const vf4*>(eps)
                     + (size_t)p0 * 1024 + 256 * w + lane;

    vf4 eA0, eA1, eA2, eA3, eB0, eB1, eB2, eB3;
    float y0, y1, y2, y3;

#define LOADQ(E0, E1, E2, E3, J) do {                                   \
        const vf4* _ep = ebase + (size_t)(J) * 1024;                     \
        E0 = _ep[0]; E1 = _ep[64]; E2 = _ep[128]; E3 = _ep[192];         \
    } while (0)

#define COMPUTE(J, E0, E1, E2, E3, Y) do {                               \
        const vf4 x4 = *reinterpret_cast<const vf4*>(&xt[(J)][4 * s]);   \
        float a0 = dot4(Wr0, x4, E0);                                    \
        float a1 = dot4(Wr1, x4, E1);                                    \
        float a2 = dot4(Wr2, x4, E2);                                    \
        float a3 = dot4(Wr3, x4, E3);                                    \
        a0 += __shfl_xor(a0, 8, 64); a1 += __shfl_xor(a1, 8, 64);        \
        a2 += __shfl_xor(a2, 8, 64); a3 += __shfl_xor(a3, 8, 64);        \
        a0 += __shfl_xor(a0, 4, 64); a1 += __shfl_xor(a1, 4, 64);        \
        a2 += __shfl_xor(a2, 4, 64); a3 += __shfl_xor(a3, 4, 64);        \
        float c0 = (s & 2) ? a2 : a0, d0 = (s & 2) ? a0 : a2;            \
        float c1 = (s & 2) ? a3 : a1, d1 = (s & 2) ? a1 : a3;            \
        c0 += __shfl_xor(d0, 2, 64); c1 += __shfl_xor(d1, 2, 64);        \
        float m  = (s & 1) ? c1 : c0, dd = (s & 1) ? c0 : c1;            \
        Y = m + __shfl_xor(dd, 1, 64) + b_fin;                           \
    } while (0)

#define STOREB(BASE) do {                                                \
        if (s < 4) {                                                     \
            vf4 yv; yv.x = y0; yv.y = y1; yv.z = y2; yv.w = y3;          \
            *reinterpret_cast<vf4*>(                                     \
                &out[(size_t)o_fin * P_TOTAL + p0 + (BASE)]) = yv;       \
        }                                                                \
    } while (0)

    // Cross-point pipelined: loads for point j+1 are in flight during
    // compute+reduce of point j; the VMEM queue never drains.
    LOADQ(eA0, eA1, eA2, eA3, 0);

    LOADQ(eB0, eB1, eB2, eB3, 1);  COMPUTE(0,  eA0, eA1, eA2, eA3, y0);
    LOADQ(eA0, eA1, eA2, eA3, 2);  COMPUTE(1,  eB0, eB1, eB2, eB3, y1);
    LOADQ(eB0, eB1, eB2, eB3, 3);  COMPUTE(2,  eA0, eA1, eA2, eA3, y2);
    LOADQ(eA0, eA1, eA2, eA3, 4);  COMPUTE(3,  eB0, eB1, eB2, eB3, y3);
    STOREB(0);
    LOADQ(eB0, eB1, eB2, eB3, 5);  COMPUTE(4,  eA0, eA1, eA2, eA3, y0);
    LOADQ(eA0, eA1, eA2, eA3, 6);  COMPUTE(5,  eB0, eB1, eB2, eB3, y1);
    LOADQ(eB0, eB1, eB2, eB3, 7);  COMPUTE(6,  eA0, eA1, eA2, eA3, y2);
    LOADQ(eA0, eA1, eA2, eA3, 8);  COMPUTE(7,  eB0, eB1, eB2, eB3, y3);
    STOREB(4);
    LOADQ(eB0, eB1, eB2, eB3, 9);  COMPUTE(8,  eA0, eA1, eA2, eA3, y0);
    LOADQ(eA0, eA1, eA2, eA3, 10); COMPUTE(9,  eB0, eB1, eB2, eB3, y1);
    LOADQ(eB0, eB1, eB2, eB3, 11); COMPUTE(10, eA0, eA1, eA2, eA3, y2);
    LOADQ(eA0, eA1, eA2, eA3, 12); COMPUTE(11, eB0, eB1, eB2, eB3, y3);
    STOREB(8);
    LOADQ(eB0, eB1, eB2, eB3, 13); COMPUTE(12, eA0, eA1, eA2, eA3, y0);
    LOADQ(eA0, eA1, eA2, eA3, 14); COMPUTE(13, eB0, eB1, eB2, eB3, y1);
    LOADQ(eB0, eB1, eB2, eB3, 15); COMPUTE(14, eA0, eA1, eA2, eA3, y2);
                                   COMPUTE(15, eB0, eB1, eB2, eB3, y3);
    STOREB(12);

#undef LOADQ
#undef COMPUTE
#undef STOREB
}

extern "C" void kernel_launch(void* const* d_in, const int* in_sizes, int n_in,
                              void* d_out, int out_size, void* d_ws, size_t ws_size,
                              hipStream_t stream) {
    const float* x    = (const float*)d_in[0];  // [64, 32768] after reshape
    const float* W    = (const float*)d_in[1];  // [64,64]
    const float* bias = (const float*)d_in[2];  // [64]
    const float* eps  = (const float*)d_in[3];  // [32768,64,64]
    float* out        = (float*)d_out;          // [64, 32768]

    dim3 grid(P_TOTAL / PPB);   // 2048 blocks
    dim3 block(256);
    noise_conv_kernel<<<grid, block, 0, stream>>>(x, W, bias, eps, out);
}